// Round 6
// baseline (86.394 us; speedup 1.0000x reference)
//
#include <hip/hip_runtime.h>

// Steerable_Encoder: separable Gaussian KDE onto a 128x128 grid.
// FM[i,j,c] = sum_n A[i,n]*B[j,n]*EY[n,c]  ->  f16 MFMA GEMM, transposed:
// D[j, (c,i)] = sum_n Bgauss[j,n] * (Agauss[i,n]*EY[n,c]),  K = 20000.
// R6: double-buffered LDS (Ag[2]/Bm[2], 55.5 KB): per chunk m,
// stage(m+1)->buf[(m+1)&1] and MFMA(m)<-buf[m&1] share one barrier window
// so exp/cvt staging overlaps MFMA across waves. __launch_bounds__(256,2).

#define NXA 128
#define NG  16384
#define NC  20000
#define KC  32            // ctx per staged chunk (2 MFMA k-steps of 16)
#define LDA 34            // f16 row stride: 68 B = 17 banks, coprime 32
#define NSL 125           // split-K slices: 125 * 160 = 20000 exactly
#define SLEN 160
#define NCHUNK 5          // SLEN / KC

#define STEP (20.0f / 127.0f)
#define KNEG (-0.72134752044448170368f)    // -0.5 * log2(e)

typedef _Float16 v8h  __attribute__((ext_vector_type(8)));
typedef float    v16f __attribute__((ext_vector_type(16)));
typedef float    v4f  __attribute__((ext_vector_type(4)));

__device__ __forceinline__ float fast_exp2(float x) {
    return __builtin_amdgcn_exp2f(x);
}

// Stage one chunk (32 ctx) into buffers from register-held X/Y float4s.
// kg = t&3 owns k-points kg*8..kg*8+7; i0 = t>>2 owns Bm rows i0, i0+64.
__device__ __forceinline__ void stage_chunk(_Float16* __restrict__ AgB,
                                            _Float16* __restrict__ BmB,
                                            const float4 xc[4], const float4 yc[4],
                                            int t, int kg, int i0,
                                            float gx0, float gx1, float gyj) {
    float xu[8], y0u[8], y1u[8];
#pragma unroll
    for (int q = 0; q < 4; ++q) {
        xu[2 * q]      = xc[q].x;  xu[2 * q + 1]  = xc[q].z;
        y0u[2 * q]     = yc[q].x;  y0u[2 * q + 1] = yc[q].z;
        y1u[2 * q]     = yc[q].y;  y1u[2 * q + 1] = yc[q].w;
    }
    v8h e, e1, e2;
#pragma unroll
    for (int u = 0; u < 8; ++u) {
        float dx = gx0 - xu[u];
        float w  = fast_exp2(dx * dx * KNEG);
        e[u]  = (_Float16)w;
        e1[u] = (_Float16)(w * y0u[u]);
        e2[u] = (_Float16)(w * y1u[u]);
    }
    *(v8h*)(BmB + i0 * LDA + kg * 8)         = e;
    *(v8h*)(BmB + (128 + i0) * LDA + kg * 8) = e1;
    *(v8h*)(BmB + (256 + i0) * LDA + kg * 8) = e2;
#pragma unroll
    for (int u = 0; u < 8; ++u) {
        float dx = gx1 - xu[u];
        float w  = fast_exp2(dx * dx * KNEG);
        e[u]  = (_Float16)w;
        e1[u] = (_Float16)(w * y0u[u]);
        e2[u] = (_Float16)(w * y1u[u]);
    }
    *(v8h*)(BmB + (64 + i0) * LDA + kg * 8)  = e;
    *(v8h*)(BmB + (192 + i0) * LDA + kg * 8) = e1;
    *(v8h*)(BmB + (320 + i0) * LDA + kg * 8) = e2;
    // Ag rows (j): waves 0-1 only
    if (t < 128) {
        v8h a;
#pragma unroll
        for (int u = 0; u < 8; ++u) {
            float x1u = xu[u];  // placeholder; overwritten below
            (void)x1u;
            float dy;
            // x1 components: (xc[u>>1].y, xc[u>>1].w) for even/odd u
            float x1 = (u & 1) ? ((u >> 1) == 0 ? xc[0].w : (u >> 1) == 1 ? xc[1].w : (u >> 1) == 2 ? xc[2].w : xc[3].w)
                               : ((u >> 1) == 0 ? xc[0].y : (u >> 1) == 1 ? xc[1].y : (u >> 1) == 2 ? xc[2].y : xc[3].y);
            dy = gyj - x1;
            a[u] = (_Float16)fast_exp2(dy * dy * KNEG);
        }
        *(v8h*)(AgB + (t >> 2) * LDA + kg * 8) = a;
    }
}

// Block: grid-j strip of 32 (position p) x all 384 (c,i) cols, one K-slice.
// Wave w covers n-cols [96w, 96w+96) as 3 tiles of 32x32.
__global__ __launch_bounds__(256, 2) void k_mfma(const float* __restrict__ X,
                                                 const float* __restrict__ Y,
                                                 float* __restrict__ fm) {
    __shared__ _Float16 Ag[2][32 * LDA];    // j-gaussian rows   [32][KC]
    __shared__ _Float16 Bm[2][384 * LDA];   // (c,i) rows: e, e*y0, e*y1

    const int t     = threadIdx.x;
    const int p     = blockIdx.x;         // 0..3 : gj base = 32p
    const int slice = blockIdx.y;         // 0..NSL-1
    const int n0    = slice * SLEN;

    const int lane = t & 63, wave = t >> 6;
    const int l31 = lane & 31, lh = lane >> 5;
    const int kg = t & 3;                 // k-group: points kg*8..kg*8+7
    const int i0 = t >> 2;                // Bm row (pass 0); +64 for pass 1
    const float gx0 = -10.f + (float)i0 * STEP;
    const float gx1 = -10.f + (float)(i0 + 64) * STEP;
    const float gyj = 10.f - (float)(32 * p + (t >> 2)) * STEP;  // for t<128

    const float4* Xp = (const float4*)X;  // float4 f covers points 2f, 2f+1
    const float4* Yp = (const float4*)Y;
    const int fb0 = (n0 >> 1) + kg * 4;   // this thread's float4 base

    v16f acc[3];
#pragma unroll
    for (int m = 0; m < 3; ++m) acc[m] = (v16f)(0.f);

    float4 xc[4], yc[4], xf[4], yf[4];
#pragma unroll
    for (int q = 0; q < 4; ++q) { xc[q] = Xp[fb0 + q];      yc[q] = Yp[fb0 + q]; }
#pragma unroll
    for (int q = 0; q < 4; ++q) { xf[q] = Xp[fb0 + 16 + q]; yf[q] = Yp[fb0 + 16 + q]; }

    // prologue: stage chunk 0 into buf 0
    stage_chunk(Ag[0], Bm[0], xc, yc, t, kg, i0, gx0, gx1, gyj);
    __syncthreads();

#pragma unroll
    for (int m = 0; m < NCHUNK; ++m) {
        // stage chunk m+1 into the other buffer (overlaps MFMA(m) across waves)
        if (m < NCHUNK - 1) {
#pragma unroll
            for (int q = 0; q < 4; ++q) { xc[q] = xf[q]; yc[q] = yf[q]; }
            if (m < NCHUNK - 2) {
                int fb = fb0 + 16 * (m + 2);
#pragma unroll
                for (int q = 0; q < 4; ++q) { xf[q] = Xp[fb + q]; yf[q] = Yp[fb + q]; }
            }
            stage_chunk(Ag[(m + 1) & 1], Bm[(m + 1) & 1], xc, yc,
                        t, kg, i0, gx0, gx1, gyj);
        }

        // MFMA on chunk m from buf[m&1]
        const _Float16* AgR = Ag[m & 1];
        const _Float16* BmR = Bm[m & 1];
#pragma unroll
        for (int s = 0; s < 2; ++s) {
            int k = s * 16 + lh * 8;
            v8h af = *(const v8h*)(AgR + l31 * LDA + k);
#pragma unroll
            for (int tn = 0; tn < 3; ++tn) {
                int n = wave * 96 + tn * 32 + l31;
                v8h bf = *(const v8h*)(BmR + n * LDA + k);
                acc[tn] = __builtin_amdgcn_mfma_f32_32x32x16_f16(af, bf, acc[tn], 0, 0, 0);
            }
        }
        if (m < NCHUNK - 1) __syncthreads();
    }

    // epilogue: D[row=j][col=(c,i)] -> fm[c][slice][gj*128 + i], contiguous in i
    const size_t cstride = (size_t)NSL * NG;
#pragma unroll
    for (int tn = 0; tn < 3; ++tn) {
        int n = wave * 96 + tn * 32 + l31;
        int c = n >> 7, i = n & 127;
        float* base = fm + (size_t)c * cstride + (size_t)slice * NG + i;
#pragma unroll
        for (int r = 0; r < 16; ++r) {
            int j  = (r & 3) + 8 * (r >> 2) + 4 * lh;
            int gj = 32 * p + j;
            base[gj * NXA] = acc[tn][r];
        }
    }
}

// reduce NSL partials, normalize, write (g' = j*128+i = out layout).
// 512 blocks x 256 thr; block owns 32 g'; thread = (q in 0..7, sg in 0..31).
__global__ __launch_bounds__(256) void k_reduce_norm(const float* __restrict__ fm,
                                                     float* __restrict__ out) {
    __shared__ v4f sAcc[3][32][8];        // 12 KB
    const int q  = threadIdx.x & 7;
    const int sg = threadIdx.x >> 3;
    const int gp = blockIdx.x * 32 + q * 4;
    const size_t cstride = (size_t)NSL * NG;
    const int per = (NSL + 31) >> 5;      // 4
    int s0 = sg * per;
    int s1 = s0 + per; if (s1 > NSL) s1 = NSL;
    v4f w = (v4f)(0.f), pp = (v4f)(0.f), qq = (v4f)(0.f);
    for (int s = s0; s < s1; ++s) {
        const float* base = fm + (size_t)s * NG + gp;
        w  += *(const v4f*)(base);
        pp += *(const v4f*)(base + cstride);
        qq += *(const v4f*)(base + 2 * cstride);
    }
    sAcc[0][sg][q] = w; sAcc[1][sg][q] = pp; sAcc[2][sg][q] = qq;
    __syncthreads();
    if (threadIdx.x < 8) {
        const int c = threadIdx.x;
        v4f W = (v4f)(0.f), P = (v4f)(0.f), Q = (v4f)(0.f);
#pragma unroll
        for (int s = 0; s < 32; ++s) {
            W += sAcc[0][s][c]; P += sAcc[1][s][c]; Q += sAcc[2][s][c];
        }
        v4f inv; inv.x = 1.f / W.x; inv.y = 1.f / W.y;
        inv.z = 1.f / W.z; inv.w = 1.f / W.w;
        const int o = blockIdx.x * 32 + c * 4;
        *(v4f*)(out + o)          = W;
        *(v4f*)(out + NG + o)     = P * inv;
        *(v4f*)(out + 2 * NG + o) = Q * inv;
    }
}

// ---- fallback (tiny ws): fp32 atomic path, known-correct ----
__global__ __launch_bounds__(256) void k_accum_atomic(const float* __restrict__ X,
                                                      const float* __restrict__ Y,
                                                      float* __restrict__ dst,
                                                      int slice_len) {
    __shared__ float As[64 * 64], Bs[64 * 64], Yl[64 * 2];
    const int t = threadIdx.x, tx = t & 15, ty = t >> 4;
    const int pos = blockIdx.x;
    const int tI = (pos >> 1) * 64, tJ = (pos & 1) * 64;
    const int n0 = blockIdx.y * slice_len;
    int nEnd = n0 + slice_len; if (nEnd > NC) nEnd = NC;
    float aw[16], ap[16], aq[16];
#pragma unroll
    for (int k = 0; k < 16; ++k) { aw[k] = ap[k] = aq[k] = 0.f; }
    for (int c0 = n0; c0 < nEnd; c0 += 64) {
        __syncthreads();
#pragma unroll
        for (int k = 0; k < 16; ++k) {
            int l = k * 256 + t, nl = l >> 6, ii = l & 63, n = c0 + nl;
            float a = 0.f, b = 0.f;
            if (n < nEnd) {
                float dx = (-10.f + (float)(tI + ii) * STEP) - X[2 * n];
                float dy = (10.f - (float)(tJ + ii) * STEP) - X[2 * n + 1];
                a = fast_exp2(dx * dx * KNEG);
                b = fast_exp2(dy * dy * KNEG);
            }
            As[nl * 64 + ii] = a; Bs[nl * 64 + ii] = b;
        }
        if (t < 128) { int n = c0 + (t >> 1); Yl[t] = (n < nEnd) ? Y[2 * n + (t & 1)] : 0.f; }
        __syncthreads();
        int cnt = nEnd - c0; if (cnt > 64) cnt = 64;
        for (int n = 0; n < cnt; ++n) {
            const float4 a4 = *(const float4*)(As + n * 64 + tx * 4);
            const float4 b4 = *(const float4*)(Bs + n * 64 + ty * 4);
            float y0 = Yl[2 * n], y1 = Yl[2 * n + 1];
            float av[4] = {a4.x, a4.y, a4.z, a4.w};
            float bv[4] = {b4.x, b4.y, b4.z, b4.w};
#pragma unroll
            for (int di = 0; di < 4; ++di)
#pragma unroll
                for (int dj = 0; dj < 4; ++dj) {
                    int k = di * 4 + dj;
                    float w = av[di] * bv[dj];
                    aw[k] += w; ap[k] = fmaf(w, y0, ap[k]); aq[k] = fmaf(w, y1, aq[k]);
                }
        }
    }
#pragma unroll
    for (int di = 0; di < 4; ++di)
#pragma unroll
        for (int dj = 0; dj < 4; ++dj) {
            int gi = tI + tx * 4 + di, gj = tJ + ty * 4 + dj;
            int o = gj * NXA + gi, k = di * 4 + dj;
            atomicAdd(dst + o, aw[k]);
            atomicAdd(dst + NG + o, ap[k]);
            atomicAdd(dst + 2 * NG + o, aq[k]);
        }
}

__global__ __launch_bounds__(256) void k_norm_inplace(float* __restrict__ out) {
    int t = blockIdx.x * 256 + threadIdx.x;
    if (t >= NG) return;
    float inv = 1.f / out[t];
    out[NG + t] *= inv; out[2 * NG + t] *= inv;
}

extern "C" void kernel_launch(void* const* d_in, const int* in_sizes, int n_in,
                              void* d_out, int out_size, void* d_ws, size_t ws_size,
                              hipStream_t stream) {
    const float* X = (const float*)d_in[0];
    const float* Y = (const float*)d_in[1];
    float* out = (float*)d_out;
    const size_t need = (size_t)NSL * NG * 3 * sizeof(float);   // 24.6 MB
    if (ws_size >= need) {
        float* fm = (float*)d_ws;
        k_mfma<<<dim3(4, NSL), 256, 0, stream>>>(X, Y, fm);
        k_reduce_norm<<<NG / 32, 256, 0, stream>>>(fm, out);
    } else {
        hipMemsetAsync(d_out, 0, (size_t)out_size * sizeof(float), stream);
        k_accum_atomic<<<dim3(4, 64), 256, 0, stream>>>(X, Y, out, (NC + 63) / 64);
        k_norm_inplace<<<(NG + 255) / 256, 256, 0, stream>>>(out);
    }
}

// Round 7
// 75.217 us; speedup vs baseline: 1.1486x; 1.1486x over previous
//
#include <hip/hip_runtime.h>

// Steerable_Encoder: separable Gaussian KDE onto a 128x128 grid.
// FM[i,j,c] = sum_n A[i,n]*B[j,n]*EY[n,c]  ->  f16 MFMA GEMM, transposed:
// D[j, (c,i)] = sum_n Bgauss[j,n] * (Agauss[i,n]*EY[n,c]),  K = 20000.
// R7: revert R6 dbuf (regressed +10us). p-pairing: block covers 64 j-rows
// (2 A-tiles, 96 accs) x 384 cols -> Bm staging shared, grid 2x125=250,
// ~40% less LDS+VALU per CU. Single-buffer, 2 barriers/chunk.

#define NXA 128
#define NG  16384
#define NC  20000
#define KC  32            // ctx per staged chunk (2 MFMA k-steps of 16)
#define LDA 34            // f16 row stride: 68 B = 17 banks, coprime 32
#define NSL 125           // split-K slices: 125 * 160 = 20000 exactly
#define SLEN 160
#define NCHUNK 5          // SLEN / KC

#define STEP (20.0f / 127.0f)
#define KNEG (-0.72134752044448170368f)    // -0.5 * log2(e)

typedef _Float16 v8h  __attribute__((ext_vector_type(8)));
typedef float    v16f __attribute__((ext_vector_type(16)));
typedef float    v4f  __attribute__((ext_vector_type(4)));

__device__ __forceinline__ float fast_exp2(float x) {
    return __builtin_amdgcn_exp2f(x);
}

// Block: grid-j strip of 64 (pp) x all 384 (c,i) cols, one K-slice of 160.
// Wave w covers n-cols [96w, 96w+96) as 3 tiles of 32, x 2 j-tiles.
__global__ __launch_bounds__(256, 1) void k_mfma(const float* __restrict__ X,
                                                 const float* __restrict__ Y,
                                                 float* __restrict__ fm) {
    __shared__ _Float16 Ag[64 * LDA];     // j-gaussian rows [64][KC]
    __shared__ _Float16 Bm[384 * LDA];    // (c,i) rows: e, e*y0, e*y1

    const int t     = threadIdx.x;
    const int pp    = blockIdx.x;         // 0..1 : gj base = 64*pp
    const int slice = blockIdx.y;         // 0..NSL-1
    const int n0    = slice * SLEN;

    const int lane = t & 63, wave = t >> 6;
    const int l31 = lane & 31, lh = lane >> 5;
    const int kg = t & 3;                 // k-group: points kg*8..kg*8+7
    const int i0 = t >> 2;                // Bm row (pass 0); +64 for pass 1
    const float gx0 = -10.f + (float)i0 * STEP;
    const float gx1 = -10.f + (float)(i0 + 64) * STEP;
    const float gyj = 10.f - (float)(64 * pp + (t >> 2)) * STEP;  // Ag row t>>2

    const float4* Xp = (const float4*)X;  // float4 f covers points 2f, 2f+1
    const float4* Yp = (const float4*)Y;
    const int fb0 = (n0 >> 1) + kg * 4;   // this thread's float4 base

    v16f acc[2][3];                       // [j-tile][n-tile]
#pragma unroll
    for (int jt = 0; jt < 2; ++jt)
#pragma unroll
        for (int m = 0; m < 3; ++m) acc[jt][m] = (v16f)(0.f);

    // prefetch chunk 0
    float4 xf[4], yf[4];
#pragma unroll
    for (int q = 0; q < 4; ++q) { xf[q] = Xp[fb0 + q]; yf[q] = Yp[fb0 + q]; }

#pragma unroll
    for (int m = 0; m < NCHUNK; ++m) {
        float4 xc[4], yc[4];
#pragma unroll
        for (int q = 0; q < 4; ++q) { xc[q] = xf[q]; yc[q] = yf[q]; }

        __syncthreads();                  // prev chunk's MFMA reads done

        if (m < NCHUNK - 1) {             // issue next chunk's loads early
            int fb = fb0 + 16 * (m + 1);
#pragma unroll
            for (int q = 0; q < 4; ++q) { xf[q] = Xp[fb + q]; yf[q] = Yp[fb + q]; }
        }

        // unpack ctx registers
        float xu[8], x1u[8], y0u[8], y1u[8];
#pragma unroll
        for (int q = 0; q < 4; ++q) {
            xu[2 * q]  = xc[q].x;  xu[2 * q + 1]  = xc[q].z;
            x1u[2 * q] = xc[q].y;  x1u[2 * q + 1] = xc[q].w;
            y0u[2 * q] = yc[q].x;  y0u[2 * q + 1] = yc[q].z;
            y1u[2 * q] = yc[q].y;  y1u[2 * q + 1] = yc[q].w;
        }

        // ---- stage Bm rows (c,i): 2 passes of 128 i, 8 k each ----
        {
            v8h e, e1, e2;
#pragma unroll
            for (int u = 0; u < 8; ++u) {
                float dx = gx0 - xu[u];
                float w  = fast_exp2(dx * dx * KNEG);
                e[u]  = (_Float16)w;
                e1[u] = (_Float16)(w * y0u[u]);
                e2[u] = (_Float16)(w * y1u[u]);
            }
            *(v8h*)(Bm + i0 * LDA + kg * 8)         = e;
            *(v8h*)(Bm + (128 + i0) * LDA + kg * 8) = e1;
            *(v8h*)(Bm + (256 + i0) * LDA + kg * 8) = e2;
#pragma unroll
            for (int u = 0; u < 8; ++u) {
                float dx = gx1 - xu[u];
                float w  = fast_exp2(dx * dx * KNEG);
                e[u]  = (_Float16)w;
                e1[u] = (_Float16)(w * y0u[u]);
                e2[u] = (_Float16)(w * y1u[u]);
            }
            *(v8h*)(Bm + (64 + i0) * LDA + kg * 8)  = e;
            *(v8h*)(Bm + (192 + i0) * LDA + kg * 8) = e1;
            *(v8h*)(Bm + (320 + i0) * LDA + kg * 8) = e2;
        }
        // ---- stage Ag rows (j): 64 rows x 4 kg = 256 tasks, all threads ----
        {
            v8h a;
#pragma unroll
            for (int u = 0; u < 8; ++u) {
                float dy = gyj - x1u[u];
                a[u] = (_Float16)fast_exp2(dy * dy * KNEG);
            }
            *(v8h*)(Ag + (t >> 2) * LDA + kg * 8) = a;
        }
        __syncthreads();

        // ---- 2 k-steps x (2 j-tiles x 3 n-tiles) of v_mfma_f32_32x32x16_f16
#pragma unroll
        for (int s = 0; s < 2; ++s) {
            int k = s * 16 + lh * 8;
            v8h af0 = *(const v8h*)(Ag + l31 * LDA + k);
            v8h af1 = *(const v8h*)(Ag + (32 + l31) * LDA + k);
#pragma unroll
            for (int tn = 0; tn < 3; ++tn) {
                int n = wave * 96 + tn * 32 + l31;
                v8h bf = *(const v8h*)(Bm + n * LDA + k);
                acc[0][tn] = __builtin_amdgcn_mfma_f32_32x32x16_f16(af0, bf, acc[0][tn], 0, 0, 0);
                acc[1][tn] = __builtin_amdgcn_mfma_f32_32x32x16_f16(af1, bf, acc[1][tn], 0, 0, 0);
            }
        }
    }

    // epilogue: D[row=j][col=(c,i)] -> fm[c][slice][gj*128 + i], contiguous in i
    const size_t cstride = (size_t)NSL * NG;
#pragma unroll
    for (int jt = 0; jt < 2; ++jt)
#pragma unroll
        for (int tn = 0; tn < 3; ++tn) {
            int n = wave * 96 + tn * 32 + l31;
            int c = n >> 7, i = n & 127;
            float* base = fm + (size_t)c * cstride + (size_t)slice * NG + i;
#pragma unroll
            for (int r = 0; r < 16; ++r) {
                int j  = (r & 3) + 8 * (r >> 2) + 4 * lh;
                int gj = 64 * pp + 32 * jt + j;
                base[gj * NXA] = acc[jt][tn][r];
            }
        }
}

// reduce NSL partials, normalize, write (g' = j*128+i = out layout).
// 512 blocks x 256 thr; block owns 32 g'; thread = (q in 0..7, sg in 0..31).
__global__ __launch_bounds__(256) void k_reduce_norm(const float* __restrict__ fm,
                                                     float* __restrict__ out) {
    __shared__ v4f sAcc[3][32][8];        // 12 KB
    const int q  = threadIdx.x & 7;
    const int sg = threadIdx.x >> 3;
    const int gp = blockIdx.x * 32 + q * 4;
    const size_t cstride = (size_t)NSL * NG;
    const int per = (NSL + 31) >> 5;      // 4
    int s0 = sg * per;
    int s1 = s0 + per; if (s1 > NSL) s1 = NSL;
    v4f w = (v4f)(0.f), pp = (v4f)(0.f), qq = (v4f)(0.f);
    for (int s = s0; s < s1; ++s) {
        const float* base = fm + (size_t)s * NG + gp;
        w  += *(const v4f*)(base);
        pp += *(const v4f*)(base + cstride);
        qq += *(const v4f*)(base + 2 * cstride);
    }
    sAcc[0][sg][q] = w; sAcc[1][sg][q] = pp; sAcc[2][sg][q] = qq;
    __syncthreads();
    if (threadIdx.x < 8) {
        const int c = threadIdx.x;
        v4f W = (v4f)(0.f), P = (v4f)(0.f), Q = (v4f)(0.f);
#pragma unroll
        for (int s = 0; s < 32; ++s) {
            W += sAcc[0][s][c]; P += sAcc[1][s][c]; Q += sAcc[2][s][c];
        }
        v4f inv; inv.x = 1.f / W.x; inv.y = 1.f / W.y;
        inv.z = 1.f / W.z; inv.w = 1.f / W.w;
        const int o = blockIdx.x * 32 + c * 4;
        *(v4f*)(out + o)          = W;
        *(v4f*)(out + NG + o)     = P * inv;
        *(v4f*)(out + 2 * NG + o) = Q * inv;
    }
}

// ---- fallback (tiny ws): fp32 atomic path, known-correct ----
__global__ __launch_bounds__(256) void k_accum_atomic(const float* __restrict__ X,
                                                      const float* __restrict__ Y,
                                                      float* __restrict__ dst,
                                                      int slice_len) {
    __shared__ float As[64 * 64], Bs[64 * 64], Yl[64 * 2];
    const int t = threadIdx.x, tx = t & 15, ty = t >> 4;
    const int pos = blockIdx.x;
    const int tI = (pos >> 1) * 64, tJ = (pos & 1) * 64;
    const int n0 = blockIdx.y * slice_len;
    int nEnd = n0 + slice_len; if (nEnd > NC) nEnd = NC;
    float aw[16], ap[16], aq[16];
#pragma unroll
    for (int k = 0; k < 16; ++k) { aw[k] = ap[k] = aq[k] = 0.f; }
    for (int c0 = n0; c0 < nEnd; c0 += 64) {
        __syncthreads();
#pragma unroll
        for (int k = 0; k < 16; ++k) {
            int l = k * 256 + t, nl = l >> 6, ii = l & 63, n = c0 + nl;
            float a = 0.f, b = 0.f;
            if (n < nEnd) {
                float dx = (-10.f + (float)(tI + ii) * STEP) - X[2 * n];
                float dy = (10.f - (float)(tJ + ii) * STEP) - X[2 * n + 1];
                a = fast_exp2(dx * dx * KNEG);
                b = fast_exp2(dy * dy * KNEG);
            }
            As[nl * 64 + ii] = a; Bs[nl * 64 + ii] = b;
        }
        if (t < 128) { int n = c0 + (t >> 1); Yl[t] = (n < nEnd) ? Y[2 * n + (t & 1)] : 0.f; }
        __syncthreads();
        int cnt = nEnd - c0; if (cnt > 64) cnt = 64;
        for (int n = 0; n < cnt; ++n) {
            const float4 a4 = *(const float4*)(As + n * 64 + tx * 4);
            const float4 b4 = *(const float4*)(Bs + n * 64 + ty * 4);
            float y0 = Yl[2 * n], y1 = Yl[2 * n + 1];
            float av[4] = {a4.x, a4.y, a4.z, a4.w};
            float bv[4] = {b4.x, b4.y, b4.z, b4.w};
#pragma unroll
            for (int di = 0; di < 4; ++di)
#pragma unroll
                for (int dj = 0; dj < 4; ++dj) {
                    int k = di * 4 + dj;
                    float w = av[di] * bv[dj];
                    aw[k] += w; ap[k] = fmaf(w, y0, ap[k]); aq[k] = fmaf(w, y1, aq[k]);
                }
        }
    }
#pragma unroll
    for (int di = 0; di < 4; ++di)
#pragma unroll
        for (int dj = 0; dj < 4; ++dj) {
            int gi = tI + tx * 4 + di, gj = tJ + ty * 4 + dj;
            int o = gj * NXA + gi, k = di * 4 + dj;
            atomicAdd(dst + o, aw[k]);
            atomicAdd(dst + NG + o, ap[k]);
            atomicAdd(dst + 2 * NG + o, aq[k]);
        }
}

__global__ __launch_bounds__(256) void k_norm_inplace(float* __restrict__ out) {
    int t = blockIdx.x * 256 + threadIdx.x;
    if (t >= NG) return;
    float inv = 1.f / out[t];
    out[NG + t] *= inv; out[2 * NG + t] *= inv;
}

extern "C" void kernel_launch(void* const* d_in, const int* in_sizes, int n_in,
                              void* d_out, int out_size, void* d_ws, size_t ws_size,
                              hipStream_t stream) {
    const float* X = (const float*)d_in[0];
    const float* Y = (const float*)d_in[1];
    float* out = (float*)d_out;
    const size_t need = (size_t)NSL * NG * 3 * sizeof(float);   // 24.6 MB
    if (ws_size >= need) {
        float* fm = (float*)d_ws;
        k_mfma<<<dim3(2, NSL), 256, 0, stream>>>(X, Y, fm);
        k_reduce_norm<<<NG / 32, 256, 0, stream>>>(fm, out);
    } else {
        hipMemsetAsync(d_out, 0, (size_t)out_size * sizeof(float), stream);
        k_accum_atomic<<<dim3(4, 64), 256, 0, stream>>>(X, Y, out, (NC + 63) / 64);
        k_norm_inplace<<<(NG + 255) / 256, 256, 0, stream>>>(out);
    }
}

// Round 8
// 72.090 us; speedup vs baseline: 1.1984x; 1.0434x over previous
//
#include <hip/hip_runtime.h>

// Steerable_Encoder: separable Gaussian KDE onto a 128x128 grid.
// FM[i,j,c] = sum_n A[i,n]*B[j,n]*EY[n,c]  ->  f16 MFMA GEMM, transposed:
// D[j, (c,i)] = sum_n Bgauss[j,n] * (Agauss[i,n]*EY[n,c]),  K = 20000.
// R8: f16 partials (12.3 MB, halves the split-K round trip), k_reduce
// rewritten for v8h f16 loads + LDS tree reduce. k_mfma main loop = R7
// (benched best: 75.2 us).

#define NXA 128
#define NG  16384
#define NC  20000
#define KC  32            // ctx per staged chunk (2 MFMA k-steps of 16)
#define LDA 34            // f16 row stride: 68 B = 17 banks, coprime 32
#define NSL 125           // split-K slices: 125 * 160 = 20000 exactly
#define SLEN 160
#define NCHUNK 5          // SLEN / KC

#define STEP (20.0f / 127.0f)
#define KNEG (-0.72134752044448170368f)    // -0.5 * log2(e)

typedef _Float16 v8h  __attribute__((ext_vector_type(8)));
typedef float    v16f __attribute__((ext_vector_type(16)));
typedef float    v4f  __attribute__((ext_vector_type(4)));

__device__ __forceinline__ float fast_exp2(float x) {
    return __builtin_amdgcn_exp2f(x);
}

// Block: grid-j strip of 64 (pp) x all 384 (c,i) cols, one K-slice of 160.
// Wave w covers n-cols [96w, 96w+96) as 3 tiles of 32, x 2 j-tiles.
__global__ __launch_bounds__(256, 1) void k_mfma(const float* __restrict__ X,
                                                 const float* __restrict__ Y,
                                                 _Float16* __restrict__ fm) {
    __shared__ _Float16 Ag[64 * LDA];     // j-gaussian rows [64][KC]
    __shared__ _Float16 Bm[384 * LDA];    // (c,i) rows: e, e*y0, e*y1

    const int t     = threadIdx.x;
    const int pp    = blockIdx.x;         // 0..1 : gj base = 64*pp
    const int slice = blockIdx.y;         // 0..NSL-1
    const int n0    = slice * SLEN;

    const int lane = t & 63, wave = t >> 6;
    const int l31 = lane & 31, lh = lane >> 5;
    const int kg = t & 3;                 // k-group: points kg*8..kg*8+7
    const int i0 = t >> 2;                // Bm row (pass 0); +64 for pass 1
    const float gx0 = -10.f + (float)i0 * STEP;
    const float gx1 = -10.f + (float)(i0 + 64) * STEP;
    const float gyj = 10.f - (float)(64 * pp + (t >> 2)) * STEP;  // Ag row t>>2

    const float4* Xp = (const float4*)X;  // float4 f covers points 2f, 2f+1
    const float4* Yp = (const float4*)Y;
    const int fb0 = (n0 >> 1) + kg * 4;   // this thread's float4 base

    v16f acc[2][3];                       // [j-tile][n-tile]
#pragma unroll
    for (int jt = 0; jt < 2; ++jt)
#pragma unroll
        for (int m = 0; m < 3; ++m) acc[jt][m] = (v16f)(0.f);

    // prefetch chunk 0
    float4 xf[4], yf[4];
#pragma unroll
    for (int q = 0; q < 4; ++q) { xf[q] = Xp[fb0 + q]; yf[q] = Yp[fb0 + q]; }

#pragma unroll
    for (int m = 0; m < NCHUNK; ++m) {
        float4 xc[4], yc[4];
#pragma unroll
        for (int q = 0; q < 4; ++q) { xc[q] = xf[q]; yc[q] = yf[q]; }

        __syncthreads();                  // prev chunk's MFMA reads done

        if (m < NCHUNK - 1) {             // issue next chunk's loads early
            int fb = fb0 + 16 * (m + 1);
#pragma unroll
            for (int q = 0; q < 4; ++q) { xf[q] = Xp[fb + q]; yf[q] = Yp[fb + q]; }
        }

        // unpack ctx registers
        float xu[8], x1u[8], y0u[8], y1u[8];
#pragma unroll
        for (int q = 0; q < 4; ++q) {
            xu[2 * q]  = xc[q].x;  xu[2 * q + 1]  = xc[q].z;
            x1u[2 * q] = xc[q].y;  x1u[2 * q + 1] = xc[q].w;
            y0u[2 * q] = yc[q].x;  y0u[2 * q + 1] = yc[q].z;
            y1u[2 * q] = yc[q].y;  y1u[2 * q + 1] = yc[q].w;
        }

        // ---- stage Bm rows (c,i): 2 passes of 128 i, 8 k each ----
        {
            v8h e, e1, e2;
#pragma unroll
            for (int u = 0; u < 8; ++u) {
                float dx = gx0 - xu[u];
                float w  = fast_exp2(dx * dx * KNEG);
                e[u]  = (_Float16)w;
                e1[u] = (_Float16)(w * y0u[u]);
                e2[u] = (_Float16)(w * y1u[u]);
            }
            *(v8h*)(Bm + i0 * LDA + kg * 8)         = e;
            *(v8h*)(Bm + (128 + i0) * LDA + kg * 8) = e1;
            *(v8h*)(Bm + (256 + i0) * LDA + kg * 8) = e2;
#pragma unroll
            for (int u = 0; u < 8; ++u) {
                float dx = gx1 - xu[u];
                float w  = fast_exp2(dx * dx * KNEG);
                e[u]  = (_Float16)w;
                e1[u] = (_Float16)(w * y0u[u]);
                e2[u] = (_Float16)(w * y1u[u]);
            }
            *(v8h*)(Bm + (64 + i0) * LDA + kg * 8)  = e;
            *(v8h*)(Bm + (192 + i0) * LDA + kg * 8) = e1;
            *(v8h*)(Bm + (320 + i0) * LDA + kg * 8) = e2;
        }
        // ---- stage Ag rows (j): 64 rows x 4 kg = 256 tasks, all threads ----
        {
            v8h a;
#pragma unroll
            for (int u = 0; u < 8; ++u) {
                float dy = gyj - x1u[u];
                a[u] = (_Float16)fast_exp2(dy * dy * KNEG);
            }
            *(v8h*)(Ag + (t >> 2) * LDA + kg * 8) = a;
        }
        __syncthreads();

        // ---- 2 k-steps x (2 j-tiles x 3 n-tiles) of v_mfma_f32_32x32x16_f16
#pragma unroll
        for (int s = 0; s < 2; ++s) {
            int k = s * 16 + lh * 8;
            v8h af0 = *(const v8h*)(Ag + l31 * LDA + k);
            v8h af1 = *(const v8h*)(Ag + (32 + l31) * LDA + k);
#pragma unroll
            for (int tn = 0; tn < 3; ++tn) {
                int n = wave * 96 + tn * 32 + l31;
                v8h bf = *(const v8h*)(Bm + n * LDA + k);
                acc[0][tn] = __builtin_amdgcn_mfma_f32_32x32x16_f16(af0, bf, acc[0][tn], 0, 0, 0);
                acc[1][tn] = __builtin_amdgcn_mfma_f32_32x32x16_f16(af1, bf, acc[1][tn], 0, 0, 0);
            }
        }
    }

    // epilogue: D[row=j][col=(c,i)] -> fm[c][slice][gj*128 + i] as f16
    const size_t cstride = (size_t)NSL * NG;
#pragma unroll
    for (int jt = 0; jt < 2; ++jt)
#pragma unroll
        for (int tn = 0; tn < 3; ++tn) {
            int n = wave * 96 + tn * 32 + l31;
            int c = n >> 7, i = n & 127;
            _Float16* base = fm + (size_t)c * cstride + (size_t)slice * NG + i;
#pragma unroll
            for (int r = 0; r < 16; ++r) {
                int j  = (r & 3) + 8 * (r >> 2) + 4 * lh;
                int gj = 64 * pp + 32 * jt + j;
                base[gj * NXA] = (_Float16)acc[jt][tn][r];
            }
        }
}

// reduce NSL f16 partials, normalize, write (g' = j*128+i = out layout).
// 512 blocks x 256 thr; block owns 32 g'; thread (q = t&3 owns 8 g' = one
// v8h load; sg = t>>2 in 0..63 owns ceil(125/64)=2 slices). f32 accumulate,
// LDS tree-reduce over sg, coalesced f32 writes.
__global__ __launch_bounds__(256) void k_reduce_norm(const _Float16* __restrict__ fm,
                                                     float* __restrict__ out) {
    __shared__ v4f sAcc[64][4][7];        // 6 used (+1 pad): [sg][q][ch*2+half]
    const int t  = threadIdx.x;
    const int q  = t & 3;
    const int sg = t >> 2;
    const int gp = blockIdx.x * 32 + q * 8;
    const size_t cstride = (size_t)NSL * NG;

    v4f a[6];
#pragma unroll
    for (int e = 0; e < 6; ++e) a[e] = (v4f)(0.f);

    const int s0 = sg * 2;
#pragma unroll
    for (int ds = 0; ds < 2; ++ds) {
        int s = s0 + ds;
        if (s < NSL) {
            const _Float16* base = fm + (size_t)s * NG + gp;
#pragma unroll
            for (int ch = 0; ch < 3; ++ch) {
                v8h v = *(const v8h*)(base + ch * cstride);
#pragma unroll
                for (int e = 0; e < 4; ++e) {
                    a[ch * 2][e]     += (float)v[e];
                    a[ch * 2 + 1][e] += (float)v[4 + e];
                }
            }
        }
    }
#pragma unroll
    for (int e = 0; e < 6; ++e) sAcc[sg][q][e] = a[e];

#pragma unroll
    for (int step = 32; step >= 1; step >>= 1) {
        __syncthreads();
        if (t < step * 4) {
            const int qq = t & 3, gg = t >> 2;
#pragma unroll
            for (int e = 0; e < 6; ++e)
                sAcc[gg][qq][e] += sAcc[gg + step][qq][e];
        }
    }
    __syncthreads();
    if (t < 4) {
        v4f Wl = sAcc[0][t][0], Wh = sAcc[0][t][1];
        v4f Pl = sAcc[0][t][2], Ph = sAcc[0][t][3];
        v4f Ql = sAcc[0][t][4], Qh = sAcc[0][t][5];
        v4f il, ih;
#pragma unroll
        for (int e = 0; e < 4; ++e) { il[e] = 1.f / Wl[e]; ih[e] = 1.f / Wh[e]; }
        const int o = blockIdx.x * 32 + t * 8;
        *(v4f*)(out + o)              = Wl;
        *(v4f*)(out + o + 4)          = Wh;
        *(v4f*)(out + NG + o)         = Pl * il;
        *(v4f*)(out + NG + o + 4)     = Ph * ih;
        *(v4f*)(out + 2 * NG + o)     = Ql * il;
        *(v4f*)(out + 2 * NG + o + 4) = Qh * ih;
    }
}

// ---- fallback (tiny ws): fp32 atomic path, known-correct ----
__global__ __launch_bounds__(256) void k_accum_atomic(const float* __restrict__ X,
                                                      const float* __restrict__ Y,
                                                      float* __restrict__ dst,
                                                      int slice_len) {
    __shared__ float As[64 * 64], Bs[64 * 64], Yl[64 * 2];
    const int t = threadIdx.x, tx = t & 15, ty = t >> 4;
    const int pos = blockIdx.x;
    const int tI = (pos >> 1) * 64, tJ = (pos & 1) * 64;
    const int n0 = blockIdx.y * slice_len;
    int nEnd = n0 + slice_len; if (nEnd > NC) nEnd = NC;
    float aw[16], ap[16], aq[16];
#pragma unroll
    for (int k = 0; k < 16; ++k) { aw[k] = ap[k] = aq[k] = 0.f; }
    for (int c0 = n0; c0 < nEnd; c0 += 64) {
        __syncthreads();
#pragma unroll
        for (int k = 0; k < 16; ++k) {
            int l = k * 256 + t, nl = l >> 6, ii = l & 63, n = c0 + nl;
            float a = 0.f, b = 0.f;
            if (n < nEnd) {
                float dx = (-10.f + (float)(tI + ii) * STEP) - X[2 * n];
                float dy = (10.f - (float)(tJ + ii) * STEP) - X[2 * n + 1];
                a = fast_exp2(dx * dx * KNEG);
                b = fast_exp2(dy * dy * KNEG);
            }
            As[nl * 64 + ii] = a; Bs[nl * 64 + ii] = b;
        }
        if (t < 128) { int n = c0 + (t >> 1); Yl[t] = (n < nEnd) ? Y[2 * n + (t & 1)] : 0.f; }
        __syncthreads();
        int cnt = nEnd - c0; if (cnt > 64) cnt = 64;
        for (int n = 0; n < cnt; ++n) {
            const float4 a4 = *(const float4*)(As + n * 64 + tx * 4);
            const float4 b4 = *(const float4*)(Bs + n * 64 + ty * 4);
            float y0 = Yl[2 * n], y1 = Yl[2 * n + 1];
            float av[4] = {a4.x, a4.y, a4.z, a4.w};
            float bv[4] = {b4.x, b4.y, b4.z, b4.w};
#pragma unroll
            for (int di = 0; di < 4; ++di)
#pragma unroll
                for (int dj = 0; dj < 4; ++dj) {
                    int k = di * 4 + dj;
                    float w = av[di] * bv[dj];
                    aw[k] += w; ap[k] = fmaf(w, y0, ap[k]); aq[k] = fmaf(w, y1, aq[k]);
                }
        }
    }
#pragma unroll
    for (int di = 0; di < 4; ++di)
#pragma unroll
        for (int dj = 0; dj < 4; ++dj) {
            int gi = tI + tx * 4 + di, gj = tJ + ty * 4 + dj;
            int o = gj * NXA + gi, k = di * 4 + dj;
            atomicAdd(dst + o, aw[k]);
            atomicAdd(dst + NG + o, ap[k]);
            atomicAdd(dst + 2 * NG + o, aq[k]);
        }
}

__global__ __launch_bounds__(256) void k_norm_inplace(float* __restrict__ out) {
    int t = blockIdx.x * 256 + threadIdx.x;
    if (t >= NG) return;
    float inv = 1.f / out[t];
    out[NG + t] *= inv; out[2 * NG + t] *= inv;
}

extern "C" void kernel_launch(void* const* d_in, const int* in_sizes, int n_in,
                              void* d_out, int out_size, void* d_ws, size_t ws_size,
                              hipStream_t stream) {
    const float* X = (const float*)d_in[0];
    const float* Y = (const float*)d_in[1];
    float* out = (float*)d_out;
    const size_t need = (size_t)NSL * NG * 3 * sizeof(_Float16);   // 12.3 MB
    if (ws_size >= need) {
        _Float16* fm = (_Float16*)d_ws;
        k_mfma<<<dim3(2, NSL), 256, 0, stream>>>(X, Y, fm);
        k_reduce_norm<<<NG / 32, 256, 0, stream>>>(fm, out);
    } else {
        hipMemsetAsync(d_out, 0, (size_t)out_size * sizeof(float), stream);
        k_accum_atomic<<<dim3(4, 64), 256, 0, stream>>>(X, Y, out, (NC + 63) / 64);
        k_norm_inplace<<<(NG + 255) / 256, 256, 0, stream>>>(out);
    }
}